// Round 19
// baseline (60.727 us; speedup 1.0000x reference)
//
#include <hip/hip_runtime.h>
#include <hip/hip_bf16.h>
#include <cstddef>

typedef __bf16 bf16;
typedef __bf16 bf16x4 __attribute__((ext_vector_type(4)));
typedef __bf16 bf16x8 __attribute__((ext_vector_type(8)));
typedef float  f32x4  __attribute__((ext_vector_type(4)));
typedef float  f32x16 __attribute__((ext_vector_type(16)));

#define NC   128
#define NS   6144
#define HD   32
#define BKV  64
#define NSPLIT 8
#define NCH  ((NS / NSPLIT) / BKV)    // 12 chunks per block
#define GELEMS (16 * NS)
// 32^-0.5 * log2(e): fold attention scale AND exp->exp2 conversion into Wq
#define QK_SCALE (0.17677669529663689f * 1.4426950408889634f)

__device__ __forceinline__ f32x4 mfma16(bf16x8 a, bf16x8 b, f32x4 c) {
  return __builtin_amdgcn_mfma_f32_16x16x32_bf16(a, b, c, 0, 0, 0);
}
__device__ __forceinline__ f32x16 mfma32(bf16x8 a, bf16x8 b, f32x16 c) {
  return __builtin_amdgcn_mfma_f32_32x32x16_bf16(a, b, c, 0, 0, 0);
}
// async global->LDS, 16B per lane; LDS dest = wave-uniform base + lane*16
__device__ __forceinline__ void gl16(const bf16* g, void* s) {
  __builtin_amdgcn_global_load_lds((const __attribute__((address_space(1))) void*)g,
                                   (__attribute__((address_space(3))) void*)s, 16, 0, 0);
}
// involution swizzle: spread 16B slots (bits[4:6]) by row bits (bits[7:9])
__device__ __forceinline__ int swz(int b) { return b ^ (((b >> 7) & 7) << 4); }
__device__ __forceinline__ unsigned cvtpk(float lo, float hi) {
  unsigned r;
  asm("v_cvt_pk_bf16_f32 %0, %1, %2" : "=v"(r) : "v"(lo), "v"(hi));
  return r;
}
__device__ __forceinline__ bf16x8 mkfrag(unsigned a, unsigned b, unsigned c, unsigned d) {
  union { unsigned u[4]; bf16x8 v; } t;
  t.u[0] = a; t.u[1] = b; t.u[2] = c; t.u[3] = d;
  return t.v;
}
// V within-64-chunk key permutation for 32x32 PV path:
// key = 16m + 8jh + 4hi + b  ->  pos = hi*32 + m*8 + jh*4 + b
__device__ __forceinline__ int vperm(int k) {
  return (((k >> 2) & 1) << 5) | (((k >> 4) & 3) << 3) | (((k >> 3) & 1) << 2) | (k & 3);
}

// ---- fused: weight prep (blocks 0..191) + group-norm partial sums (192..287) ----
__global__ __launch_bounds__(256) void k_prep_stats(
    const float* __restrict__ qkv_w, const float* __restrict__ qkv_b,
    const float* __restrict__ proj_w, const float* __restrict__ x,
    bf16* __restrict__ wq, bf16* __restrict__ wp, float* __restrict__ bias_s,
    float* __restrict__ partials) {
  int bid = blockIdx.x;
  int tid = threadIdx.x;
  if (bid < 192) {
    int i = bid * 256 + tid;
    if (i < 3 * NC * NC) {
      float v = qkv_w[i];
      if (i < NC * NC) v *= QK_SCALE;
      wq[i] = (bf16)v;
    }
    if (i < NC * NC) wp[i] = (bf16)proj_w[i];
    if (i < 3 * NC) bias_s[i] = qkv_b[i] * ((i < NC) ? QK_SCALE : 1.0f);
    return;
  }
  int b = bid - 192;
  int g = b / 12, chunk = b % 12;
  float sum = 0.f, sq = 0.f;
  #pragma unroll
  for (int k = 0; k < 8; ++k) {
    int f4 = tid + k * 256;
    int c  = f4 >> 7;
    int s4 = f4 & 127;
    const float4 v = ((const float4*)x)[(size_t)(g * 16 + c) * (NS / 4) + chunk * 128 + s4];
    sum += v.x + v.y + v.z + v.w;
    sq  += v.x * v.x + v.y * v.y + v.z * v.z + v.w * v.w;
  }
  #pragma unroll
  for (int off = 32; off; off >>= 1) {
    sum += __shfl_down(sum, off, 64);
    sq  += __shfl_down(sq,  off, 64);
  }
  __shared__ float red[2][4];
  if ((tid & 63) == 0) { red[0][tid >> 6] = sum; red[1][tid >> 6] = sq; }
  __syncthreads();
  if (tid == 0) {
    partials[b * 2 + 0] = red[0][0] + red[0][1] + red[0][2] + red[0][3];
    partials[b * 2 + 1] = red[1][0] + red[1][1] + red[1][2] + red[1][3];
  }
}

// ---- fused GN-apply + QKV GEMM; epilogue via LDS transpose -> coalesced stores ----
// outputs: qg,kg [h][s][32]; v transposed vtg [h][c][s] with key perm (vperm)
__global__ __launch_bounds__(256) void k_qkv(
    const float* __restrict__ x, const float* __restrict__ partials,
    const float* __restrict__ gn_w, const float* __restrict__ gn_b,
    const bf16* __restrict__ wq, const float* __restrict__ bias_s,
    bf16* __restrict__ qg, bf16* __restrict__ kg, bf16* __restrict__ vtg) {
  int ot = blockIdx.x;            // 0..5
  int st = blockIdx.y;            // 0..95
  int tid = threadIdx.x;
  __shared__ __align__(16) char xn[64 * 256];   // swizzled [s][c] input tile; reused by epilogue
  __shared__ float swc[NC], sbc[NC];

  if (tid < NC) {
    int g = tid >> 4;
    float sum = 0.f, sq = 0.f;
    #pragma unroll
    for (int i = 0; i < 12; ++i) {
      sum += partials[(g * 12 + i) * 2 + 0];
      sq  += partials[(g * 12 + i) * 2 + 1];
    }
    float mean = sum * (1.0f / GELEMS);
    float var  = sq  * (1.0f / GELEMS) - mean * mean;
    float rstd = rsqrtf(var + 1e-5f);
    float wc = gn_w[tid] * rstd;
    swc[tid] = wc;
    sbc[tid] = gn_b[tid] - mean * wc;
  }
  __syncthreads();

  int s_local = tid & 63;
  int s_glob  = st * 64 + s_local;
  int wk = tid >> 6;
  #pragma unroll
  for (int i = 0; i < 4; ++i) {
    int c0 = (wk * 4 + i) * 8;
    bf16x8 ov;
    #pragma unroll
    for (int j = 0; j < 8; ++j) {
      int c = c0 + j;
      ov[j] = (bf16)(x[(size_t)c * NS + s_glob] * swc[c] + sbc[c]);
    }
    *(bf16x8*)(xn + ((s_local * 256 + c0 * 2) ^ ((s_local & 7) << 4))) = ov;
  }
  __syncthreads();

  int w = tid >> 6, l = tid & 63;
  int lr = l & 15, lg = l >> 4;
  int o_base = ot * 64 + (w >> 1) * 32;
  int sl_base = (w & 1) * 32;
  f32x4 acc[2][2] = {};
  #pragma unroll
  for (int k0 = 0; k0 < NC; k0 += 32) {
    bf16x8 a[2], b[2];
    #pragma unroll
    for (int m = 0; m < 2; ++m)
      a[m] = *(const bf16x8*)(wq + (size_t)(o_base + m * 16 + lr) * NC + k0 + lg * 8);
    #pragma unroll
    for (int n = 0; n < 2; ++n) {
      int row = sl_base + n * 16 + lr;
      b[n] = *(const bf16x8*)(xn + ((row * 256 + (k0 + lg * 8) * 2) ^ ((row & 7) << 4)));
    }
    #pragma unroll
    for (int m = 0; m < 2; ++m)
      #pragma unroll
      for (int n = 0; n < 2; ++n)
        acc[m][n] = mfma16(a[m], b[n], acc[m][n]);
  }

  // ---- epilogue: stage tile in LDS (pitch 72 bf16), then coalesced stores ----
  __syncthreads();                 // xn reads done; reuse as out tile
  bf16* ot_lds = (bf16*)xn;        // q/k: [s_local][o_local]; v: [c_local][pos]
  const bool is_v = (ot >= 4);
  #pragma unroll
  for (int m = 0; m < 2; ++m)
    #pragma unroll
    for (int n = 0; n < 2; ++n)
      #pragma unroll
      for (int r = 0; r < 4; ++r) {
        int o_l = (w >> 1) * 32 + m * 16 + lg * 4 + r;
        int s_l = (w & 1) * 32 + n * 16 + lr;
        int o = ot * 64 + o_l;
        bf16 v = (bf16)(acc[m][n][r] + bias_s[o]);
        if (is_v) ot_lds[o_l * 72 + vperm(s_l)] = v;   // [c][pos]
        else      ot_lds[s_l * 72 + o_l]        = v;   // [s][o]
      }
  __syncthreads();

  if (!is_v) {
    bf16* dst = (ot < 2) ? qg : kg;
    int head0 = (ot & 1) * 2;
    int c8 = tid & 3, s_l = tid >> 2;
    size_t s = (size_t)st * 64 + s_l;
    #pragma unroll
    for (int i = 0; i < 2; ++i) {
      bf16x8 v = *(const bf16x8*)(ot_lds + s_l * 72 + i * 32 + c8 * 8);
      *(bf16x8*)(dst + ((size_t)(head0 + i) * NS + s) * HD + c8 * 8) = v;
    }
  } else {
    int head0 = (ot - 4) * 2;
    int c_l = tid >> 2;
    int head = head0 + (c_l >> 5), c32 = c_l & 31;
    bf16* drow = vtg + ((size_t)head * HD + c32) * NS + st * 64;
    #pragma unroll
    for (int i = 0; i < 2; ++i) {
      int pos8 = (tid & 3) * 2 + i;
      bf16x8 v = *(const bf16x8*)(ot_lds + c_l * 72 + pos8 * 8);
      *(bf16x8*)(drow + pos8 * 8) = v;
    }
  }
}

// ---- flash attention: 32x32 MFMA (32 q-rows/wave), fixed-m softmax, K/V
//      LDS-staged, P in registers (permuted keys), V pre-permuted -> 1 b128/frag,
//      DUAL O accumulators (halved PV chain), split-KV x8 ----
__global__ __launch_bounds__(256, 4) void k_attn(
    const bf16* __restrict__ qg, const bf16* __restrict__ kg, const bf16* __restrict__ vtg,
    bf16* __restrict__ accP, float* __restrict__ ml) {
  const int h = blockIdx.y, sp = blockIdx.z;
  const int tid = threadIdx.x;
  const int w = tid >> 6, l = tid & 63;
  const int l31 = l & 31, hi = l >> 5;
  const int qrow0 = blockIdx.x * 128 + w * 32;

  __shared__ __align__(16) char kbuf[2][4096];   // K chunk [64 key][32 c], swizzled
  __shared__ __align__(16) char vbuf[2][4096];   // V^T chunk [32 c][64 pos], swizzled
  const int kswz = ((l31 >> 1) & 7) << 4;
  const int vswz = (l31 & 7) << 4;
  const int ka0  = (l31 * 64 + hi * 16) ^ kswz;        // kt0 c-slice0 (+2048: kt1)
  const int ka1  = (l31 * 64 + 32 + hi * 16) ^ kswz;   // kt0 c-slice1

  const bf16* qp = qg + (size_t)h * NS * HD;
  const bf16* kp = kg + (size_t)h * NS * HD;
  const bf16* vp = vtg + (size_t)h * HD * NS;

  // Q as B of mfma32(K,Q): lane holds Q[qrow0+l31][slice*16 + hi*8 + j]
  bf16x8 qf0 = *(const bf16x8*)(qp + (size_t)(qrow0 + l31) * HD + hi * 8);
  bf16x8 qf1 = *(const bf16x8*)(qp + (size_t)(qrow0 + l31) * HD + 16 + hi * 8);

  f32x16 Ot0 = {}, Ot1 = {};           // O^T halves: col q = l31, rows c
  float l_r = 0.f;                     // per-lane l partial (this lane's 32 keys/chunk)
  const f32x16 zed16 = {};
  const int kv_beg = sp * (NS / NSPLIT);

  // staging source mapping (pre-swizzled involution, validated R5-R18)
  const int o_st = w * 1024 + (l << 4);
  const int u_st = swz(o_st);
  const bf16* ksrc = kp + (size_t)(kv_beg + (u_st >> 6)) * HD + ((u_st & 63) >> 1);
  const bf16* vsrc = vp + (size_t)(u_st >> 7) * NS + kv_beg + ((u_st & 127) >> 1);

  f32x16 sv0, sv1;
  bf16x8 pf0, pf1, pf2, pf3;  // P^T B-frags; group m keys: 16m + 8(j>>2)+4hi+(j&3)

  // fixed-m softmax + in-register pack (exp2 in place) + VALU l-sum
  auto packP = [&](f32x16& sv, bf16x8& fA, bf16x8& fB) {
    #pragma unroll
    for (int r = 0; r < 16; ++r) sv[r] = __builtin_amdgcn_exp2f(sv[r]);
    l_r += (((sv[0] + sv[1]) + (sv[2] + sv[3])) + ((sv[4] + sv[5]) + (sv[6] + sv[7])))
         + (((sv[8] + sv[9]) + (sv[10] + sv[11])) + ((sv[12] + sv[13]) + (sv[14] + sv[15])));
    fA = mkfrag(cvtpk(sv[0], sv[1]),  cvtpk(sv[2], sv[3]),
                cvtpk(sv[4], sv[5]),  cvtpk(sv[6], sv[7]));
    fB = mkfrag(cvtpk(sv[8], sv[9]),  cvtpk(sv[10], sv[11]),
                cvtpk(sv[12], sv[13]), cvtpk(sv[14], sv[15]));
  };
  // V A-frag group m: pos = hi*32 + m*8 + j contiguous -> single b128
  auto vfrag = [&](const char* vb, int m) -> bf16x8 {
    return *(const bf16x8*)(vb + ((l31 * 128 + hi * 64 + m * 16) ^ vswz));
  };
  auto qk = [&](const char* kb) {
    sv0 = mfma32(*(const bf16x8*)(kb + ka0), qf0, zed16);
    sv0 = mfma32(*(const bf16x8*)(kb + ka1), qf1, sv0);
    sv1 = mfma32(*(const bf16x8*)(kb + ka0 + 2048), qf0, zed16);
    sv1 = mfma32(*(const bf16x8*)(kb + ka1 + 2048), qf1, sv1);
  };

  // prologue: stage K(0), V(0), K(1); QK(0); pack(0)
  gl16(ksrc, kbuf[0] + w * 1024);
  gl16(vsrc, vbuf[0] + w * 1024);
  gl16(ksrc + BKV * HD, kbuf[1] + w * 1024);
  __syncthreads();
  qk(kbuf[0]);
  packP(sv0, pf0, pf1);
  packP(sv1, pf2, pf3);

  for (int t = 0; t < NCH; ++t) {
    const int cur = t & 1, nxt = cur ^ 1;
    const bool hn = (t + 1 < NCH);
    __syncthreads();
    // staging at chunk top: drain at next barrier sees chunk-old loads
    if (hn) gl16(vsrc + (size_t)(t + 1) * BKV, vbuf[nxt] + w * 1024);
    if (t + 2 < NCH) gl16(ksrc + (size_t)(t + 2) * BKV * HD, kbuf[cur] + w * 1024);
    // QK(t+1): writes sv (pf still holds P(t))
    if (hn) qk(kbuf[nxt]);
    // PV(t): two independent 2-chains on Ot0/Ot1
    {
      const char* vb = vbuf[cur];
      Ot0 = mfma32(vfrag(vb, 0), pf0, Ot0);
      Ot1 = mfma32(vfrag(vb, 1), pf1, Ot1);
      Ot0 = mfma32(vfrag(vb, 2), pf2, Ot0);
      Ot1 = mfma32(vfrag(vb, 3), pf3, Ot1);
    }
    // pack(t+1): overwrites pf AFTER PV(t) consumed it
    if (hn) {
      packP(sv0, pf0, pf1);
      packP(sv1, pf2, pf3);
    }
  }

  // lane holds 32 of 64 keys/chunk; partner hi^1 holds the rest
  l_r += __shfl_xor(l_r, 32, 64);

  // store unnormalized O^T partials, layout [h][sp][cg(8)][s][4] bf16
  // Ot reg r: c = (r&3) + 8*(r>>2) + 4*hi -> cg = hi + 2*(r>>2), idx = r&3
  bf16* base = accP + (size_t)(h * NSPLIT + sp) * 8 * NS * 4;
  size_t qrow = qrow0 + l31;
  #pragma unroll
  for (int m = 0; m < 4; ++m) {
    bf16x4 ov;
    #pragma unroll
    for (int j = 0; j < 4; ++j) ov[j] = (bf16)(Ot0[4 * m + j] + Ot1[4 * m + j]);
    *(bf16x4*)(base + ((size_t)(hi + 2 * m) * NS + qrow) * 4) = ov;
  }
  if (hi == 0)
    ml[(size_t)(h * NSPLIT + sp) * NS + qrow] = l_r;
}

// ---- fused combine + proj GEMM + bias + residual + mask; 32-wide s tiles ----
__global__ __launch_bounds__(256) void k_proj(
    const bf16* __restrict__ wp, const bf16* __restrict__ accP, const float* __restrict__ ml,
    const float* __restrict__ proj_b, const float* __restrict__ x,
    const float* __restrict__ mask, float* __restrict__ out) {
  int ot = blockIdx.x;            // 0..1
  int st = blockIdx.y;            // 0..191 (32-wide s tiles)
  int tid = threadIdx.x;
  __shared__ __align__(16) char at[32 * 256];   // swizzled [s][c] bf16 tile

  int s_local = tid >> 3;         // 0..31
  int s = st * 32 + s_local;
  if (ot == 0 && tid < 32)        // mask passthrough (second output)
    out[(size_t)NC * NS + st * 32 + tid] = mask[st * 32 + tid];
  #pragma unroll
  for (int i = 0; i < 2; ++i) {
    int c0 = ((tid & 7) * 2 + i) * 8;
    int h = c0 >> 5;
    float L = 0.f;
    #pragma unroll
    for (int spl = 0; spl < NSPLIT; ++spl)
      L += ml[(size_t)(h * NSPLIT + spl) * NS + s];
    float inv = 1.0f / L;
    float o[8] = {};
    int cg0 = (c0 & 31) >> 2;
    #pragma unroll
    for (int spl = 0; spl < NSPLIT; ++spl) {
      const bf16* bp = accP + ((size_t)((h * NSPLIT + spl) * 8 + cg0) * NS + s) * 4;
      bf16x4 a0 = *(const bf16x4*)(bp);
      bf16x4 a1 = *(const bf16x4*)(bp + (size_t)NS * 4);
      #pragma unroll
      for (int j = 0; j < 4; ++j) {
        o[j]     += (float)a0[j];
        o[4 + j] += (float)a1[j];
      }
    }
    bf16x8 ov;
    #pragma unroll
    for (int j = 0; j < 8; ++j) ov[j] = (bf16)(o[j] * inv);
    *(bf16x8*)(at + ((s_local * 256 + c0 * 2) ^ ((s_local & 7) << 4))) = ov;
  }
  __syncthreads();

  int w = tid >> 6, l = tid & 63;
  int lr = l & 15, lg = l >> 4;
  int o_base = ot * 64 + (w >> 1) * 32;
  int sl_base = (w & 1) * 16;
  f32x4 acc[2] = {};
  #pragma unroll
  for (int k0 = 0; k0 < NC; k0 += 32) {
    bf16x8 a[2], b;
    #pragma unroll
    for (int m = 0; m < 2; ++m)
      a[m] = *(const bf16x8*)(wp + (size_t)(o_base + m * 16 + lr) * NC + k0 + lg * 8);
    {
      int row = sl_base + lr;
      b = *(const bf16x8*)(at + ((row * 256 + (k0 + lg * 8) * 2) ^ ((row & 7) << 4)));
    }
    #pragma unroll
    for (int m = 0; m < 2; ++m)
      acc[m] = mfma16(a[m], b, acc[m]);
  }
  #pragma unroll
  for (int m = 0; m < 2; ++m)
    #pragma unroll
    for (int r = 0; r < 4; ++r) {
      int o = o_base + m * 16 + lg * 4 + r;
      int sg = st * 32 + sl_base + lr;
      float v = acc[m][r] + proj_b[o] + x[(size_t)o * NS + sg];
      out[(size_t)o * NS + sg] = v * mask[sg];
    }
}

extern "C" void kernel_launch(void* const* d_in, const int* in_sizes, int n_in,
                              void* d_out, int out_size, void* d_ws, size_t ws_size,
                              hipStream_t stream) {
  const float* x      = (const float*)d_in[0];
  const float* mask   = (const float*)d_in[1];
  const float* gn_w   = (const float*)d_in[2];
  const float* gn_b   = (const float*)d_in[3];
  const float* qkv_w  = (const float*)d_in[4];
  const float* qkv_b  = (const float*)d_in[5];
  const float* proj_w = (const float*)d_in[6];
  const float* proj_b = (const float*)d_in[7];

  char* ws = (char*)d_ws;
  float* partials = (float*)(ws + 0);            //     768 B
  float* bias_s   = (float*)(ws + 1024);         //    1536 B
  bf16*  wq       = (bf16*)(ws + 4096);          //   98304 B
  bf16*  wp       = (bf16*)(ws + 102400);        //   32768 B
  bf16*  qg       = (bf16*)(ws + 135168);        // 1.50 MB [h][s][32]
  bf16*  kg       = (bf16*)(ws + 1708032);       // 1.50 MB [h][s][32]
  bf16*  vtg      = (bf16*)(ws + 3280896);       // 1.50 MB [h][c][s] (key-permuted)
  bf16*  accP     = (bf16*)(ws + 4853760);       // 12.58 MB [h][sp][cg][s][4]
  float* ml       = (float*)(ws + 17436672);     // 786 KB   [h][sp][s]
  float* out      = (float*)d_out;

  k_prep_stats<<<288, 256, 0, stream>>>(qkv_w, qkv_b, proj_w, x, wq, wp, bias_s, partials);
  k_qkv       <<<dim3(6, 96), 256, 0, stream>>>(x, partials, gn_w, gn_b, wq, bias_s, qg, kg, vtg);
  k_attn      <<<dim3(48, 4, NSPLIT), 256, 0, stream>>>(qg, kg, vtg, accP, ml);
  k_proj      <<<dim3(2, 192), 256, 0, stream>>>(wp, accP, ml, proj_b, x, mask, out);
}

// Round 20
// 57.119 us; speedup vs baseline: 1.0632x; 1.0632x over previous
//
#include <hip/hip_runtime.h>
#include <hip/hip_bf16.h>
#include <cstddef>

typedef __bf16 bf16;
typedef __bf16 bf16x4 __attribute__((ext_vector_type(4)));
typedef __bf16 bf16x8 __attribute__((ext_vector_type(8)));
typedef float  f32x4  __attribute__((ext_vector_type(4)));
typedef float  f32x16 __attribute__((ext_vector_type(16)));

#define NC   128
#define NS   6144
#define HD   32
#define BKV  64
#define NSPLIT 4
#define NCH  ((NS / NSPLIT) / BKV)    // 24 chunks per block
#define GELEMS (16 * NS)
// 32^-0.5 * log2(e): fold attention scale AND exp->exp2 conversion into Wq
#define QK_SCALE (0.17677669529663689f * 1.4426950408889634f)

__device__ __forceinline__ f32x4 mfma16(bf16x8 a, bf16x8 b, f32x4 c) {
  return __builtin_amdgcn_mfma_f32_16x16x32_bf16(a, b, c, 0, 0, 0);
}
__device__ __forceinline__ f32x16 mfma32(bf16x8 a, bf16x8 b, f32x16 c) {
  return __builtin_amdgcn_mfma_f32_32x32x16_bf16(a, b, c, 0, 0, 0);
}
// async global->LDS, 16B per lane; LDS dest = wave-uniform base + lane*16
__device__ __forceinline__ void gl16(const bf16* g, void* s) {
  __builtin_amdgcn_global_load_lds((const __attribute__((address_space(1))) void*)g,
                                   (__attribute__((address_space(3))) void*)s, 16, 0, 0);
}
// involution swizzle: spread 16B slots (bits[4:6]) by row bits (bits[7:9])
__device__ __forceinline__ int swz(int b) { return b ^ (((b >> 7) & 7) << 4); }
__device__ __forceinline__ unsigned cvtpk(float lo, float hi) {
  unsigned r;
  asm("v_cvt_pk_bf16_f32 %0, %1, %2" : "=v"(r) : "v"(lo), "v"(hi));
  return r;
}
__device__ __forceinline__ bf16x8 mkfrag(unsigned a, unsigned b, unsigned c, unsigned d) {
  union { unsigned u[4]; bf16x8 v; } t;
  t.u[0] = a; t.u[1] = b; t.u[2] = c; t.u[3] = d;
  return t.v;
}
// V within-64-chunk key permutation for 32x32 PV path:
// key = 16m + 8jh + 4hi + b  ->  pos = hi*32 + m*8 + jh*4 + b
__device__ __forceinline__ int vperm(int k) {
  return (((k >> 2) & 1) << 5) | (((k >> 4) & 3) << 3) | (((k >> 3) & 1) << 2) | (k & 3);
}

// ---- fused: weight prep (blocks 0..191) + group-norm partial sums (192..287) ----
__global__ __launch_bounds__(256) void k_prep_stats(
    const float* __restrict__ qkv_w, const float* __restrict__ qkv_b,
    const float* __restrict__ proj_w, const float* __restrict__ x,
    bf16* __restrict__ wq, bf16* __restrict__ wp, float* __restrict__ bias_s,
    float* __restrict__ partials) {
  int bid = blockIdx.x;
  int tid = threadIdx.x;
  if (bid < 192) {
    int i = bid * 256 + tid;
    if (i < 3 * NC * NC) {
      float v = qkv_w[i];
      if (i < NC * NC) v *= QK_SCALE;
      wq[i] = (bf16)v;
    }
    if (i < NC * NC) wp[i] = (bf16)proj_w[i];
    if (i < 3 * NC) bias_s[i] = qkv_b[i] * ((i < NC) ? QK_SCALE : 1.0f);
    return;
  }
  int b = bid - 192;
  int g = b / 12, chunk = b % 12;
  float sum = 0.f, sq = 0.f;
  #pragma unroll
  for (int k = 0; k < 8; ++k) {
    int f4 = tid + k * 256;
    int c  = f4 >> 7;
    int s4 = f4 & 127;
    const float4 v = ((const float4*)x)[(size_t)(g * 16 + c) * (NS / 4) + chunk * 128 + s4];
    sum += v.x + v.y + v.z + v.w;
    sq  += v.x * v.x + v.y * v.y + v.z * v.z + v.w * v.w;
  }
  #pragma unroll
  for (int off = 32; off; off >>= 1) {
    sum += __shfl_down(sum, off, 64);
    sq  += __shfl_down(sq,  off, 64);
  }
  __shared__ float red[2][4];
  if ((tid & 63) == 0) { red[0][tid >> 6] = sum; red[1][tid >> 6] = sq; }
  __syncthreads();
  if (tid == 0) {
    partials[b * 2 + 0] = red[0][0] + red[0][1] + red[0][2] + red[0][3];
    partials[b * 2 + 1] = red[1][0] + red[1][1] + red[1][2] + red[1][3];
  }
}

// ---- fused GN-apply + QKV GEMM; epilogue via LDS transpose -> coalesced stores ----
// outputs: qg,kg [h][s][32]; v transposed vtg [h][c][s] with key perm (vperm)
__global__ __launch_bounds__(256) void k_qkv(
    const float* __restrict__ x, const float* __restrict__ partials,
    const float* __restrict__ gn_w, const float* __restrict__ gn_b,
    const bf16* __restrict__ wq, const float* __restrict__ bias_s,
    bf16* __restrict__ qg, bf16* __restrict__ kg, bf16* __restrict__ vtg) {
  int ot = blockIdx.x;            // 0..5
  int st = blockIdx.y;            // 0..95
  int tid = threadIdx.x;
  __shared__ __align__(16) char xn[64 * 256];   // swizzled [s][c] input tile; reused by epilogue
  __shared__ float swc[NC], sbc[NC];

  if (tid < NC) {
    int g = tid >> 4;
    float sum = 0.f, sq = 0.f;
    #pragma unroll
    for (int i = 0; i < 12; ++i) {
      sum += partials[(g * 12 + i) * 2 + 0];
      sq  += partials[(g * 12 + i) * 2 + 1];
    }
    float mean = sum * (1.0f / GELEMS);
    float var  = sq  * (1.0f / GELEMS) - mean * mean;
    float rstd = rsqrtf(var + 1e-5f);
    float wc = gn_w[tid] * rstd;
    swc[tid] = wc;
    sbc[tid] = gn_b[tid] - mean * wc;
  }
  __syncthreads();

  int s_local = tid & 63;
  int s_glob  = st * 64 + s_local;
  int wk = tid >> 6;
  #pragma unroll
  for (int i = 0; i < 4; ++i) {
    int c0 = (wk * 4 + i) * 8;
    bf16x8 ov;
    #pragma unroll
    for (int j = 0; j < 8; ++j) {
      int c = c0 + j;
      ov[j] = (bf16)(x[(size_t)c * NS + s_glob] * swc[c] + sbc[c]);
    }
    *(bf16x8*)(xn + ((s_local * 256 + c0 * 2) ^ ((s_local & 7) << 4))) = ov;
  }
  __syncthreads();

  int w = tid >> 6, l = tid & 63;
  int lr = l & 15, lg = l >> 4;
  int o_base = ot * 64 + (w >> 1) * 32;
  int sl_base = (w & 1) * 32;
  f32x4 acc[2][2] = {};
  #pragma unroll
  for (int k0 = 0; k0 < NC; k0 += 32) {
    bf16x8 a[2], b[2];
    #pragma unroll
    for (int m = 0; m < 2; ++m)
      a[m] = *(const bf16x8*)(wq + (size_t)(o_base + m * 16 + lr) * NC + k0 + lg * 8);
    #pragma unroll
    for (int n = 0; n < 2; ++n) {
      int row = sl_base + n * 16 + lr;
      b[n] = *(const bf16x8*)(xn + ((row * 256 + (k0 + lg * 8) * 2) ^ ((row & 7) << 4)));
    }
    #pragma unroll
    for (int m = 0; m < 2; ++m)
      #pragma unroll
      for (int n = 0; n < 2; ++n)
        acc[m][n] = mfma16(a[m], b[n], acc[m][n]);
  }

  // ---- epilogue: stage tile in LDS (pitch 72 bf16), then coalesced stores ----
  __syncthreads();                 // xn reads done; reuse as out tile
  bf16* ot_lds = (bf16*)xn;        // q/k: [s_local][o_local]; v: [c_local][pos]
  const bool is_v = (ot >= 4);
  #pragma unroll
  for (int m = 0; m < 2; ++m)
    #pragma unroll
    for (int n = 0; n < 2; ++n)
      #pragma unroll
      for (int r = 0; r < 4; ++r) {
        int o_l = (w >> 1) * 32 + m * 16 + lg * 4 + r;
        int s_l = (w & 1) * 32 + n * 16 + lr;
        int o = ot * 64 + o_l;
        bf16 v = (bf16)(acc[m][n][r] + bias_s[o]);
        if (is_v) ot_lds[o_l * 72 + vperm(s_l)] = v;   // [c][pos]
        else      ot_lds[s_l * 72 + o_l]        = v;   // [s][o]
      }
  __syncthreads();

  if (!is_v) {
    bf16* dst = (ot < 2) ? qg : kg;
    int head0 = (ot & 1) * 2;
    int c8 = tid & 3, s_l = tid >> 2;
    size_t s = (size_t)st * 64 + s_l;
    #pragma unroll
    for (int i = 0; i < 2; ++i) {
      bf16x8 v = *(const bf16x8*)(ot_lds + s_l * 72 + i * 32 + c8 * 8);
      *(bf16x8*)(dst + ((size_t)(head0 + i) * NS + s) * HD + c8 * 8) = v;
    }
  } else {
    int head0 = (ot - 4) * 2;
    int c_l = tid >> 2;
    int head = head0 + (c_l >> 5), c32 = c_l & 31;
    bf16* drow = vtg + ((size_t)head * HD + c32) * NS + st * 64;
    #pragma unroll
    for (int i = 0; i < 2; ++i) {
      int pos8 = (tid & 3) * 2 + i;
      bf16x8 v = *(const bf16x8*)(ot_lds + c_l * 72 + pos8 * 8);
      *(bf16x8*)(drow + pos8 * 8) = v;
    }
  }
}

// ---- flash attention: 32x32 MFMA (32 q-rows/wave), fixed-m softmax, K/V
//      LDS-staged, P in registers (permuted keys), V pre-permuted -> 1 b128/frag,
//      dual O accumulators; launch_bounds (256,3): grid is 3 blocks/CU anyway,
//      so the relaxed VGPR cap (~170) costs nothing and avoids spills ----
__global__ __launch_bounds__(256, 3) void k_attn(
    const bf16* __restrict__ qg, const bf16* __restrict__ kg, const bf16* __restrict__ vtg,
    bf16* __restrict__ accP, float* __restrict__ ml) {
  const int h = blockIdx.y, sp = blockIdx.z;
  const int tid = threadIdx.x;
  const int w = tid >> 6, l = tid & 63;
  const int l31 = l & 31, hi = l >> 5;
  const int qrow0 = blockIdx.x * 128 + w * 32;

  __shared__ __align__(16) char kbuf[2][4096];   // K chunk [64 key][32 c], swizzled
  __shared__ __align__(16) char vbuf[2][4096];   // V^T chunk [32 c][64 pos], swizzled
  const int kswz = ((l31 >> 1) & 7) << 4;
  const int vswz = (l31 & 7) << 4;
  const int ka0  = (l31 * 64 + hi * 16) ^ kswz;        // kt0 c-slice0 (+2048: kt1)
  const int ka1  = (l31 * 64 + 32 + hi * 16) ^ kswz;   // kt0 c-slice1

  const bf16* qp = qg + (size_t)h * NS * HD;
  const bf16* kp = kg + (size_t)h * NS * HD;
  const bf16* vp = vtg + (size_t)h * HD * NS;

  // Q as B of mfma32(K,Q): lane holds Q[qrow0+l31][slice*16 + hi*8 + j]
  bf16x8 qf0 = *(const bf16x8*)(qp + (size_t)(qrow0 + l31) * HD + hi * 8);
  bf16x8 qf1 = *(const bf16x8*)(qp + (size_t)(qrow0 + l31) * HD + 16 + hi * 8);

  f32x16 Ot0 = {}, Ot1 = {};           // O^T halves: col q = l31, rows c
  float l_r = 0.f;                     // per-lane l partial (this lane's 32 keys/chunk)
  const f32x16 zed16 = {};
  const int kv_beg = sp * (NS / NSPLIT);

  // staging source mapping (pre-swizzled involution, validated R5-R18)
  const int o_st = w * 1024 + (l << 4);
  const int u_st = swz(o_st);
  const bf16* ksrc = kp + (size_t)(kv_beg + (u_st >> 6)) * HD + ((u_st & 63) >> 1);
  const bf16* vsrc = vp + (size_t)(u_st >> 7) * NS + kv_beg + ((u_st & 127) >> 1);

  f32x16 sv0, sv1;
  bf16x8 pf0, pf1, pf2, pf3;  // P^T B-frags; group m keys: 16m + 8(j>>2)+4hi+(j&3)

  // fixed-m softmax + in-register pack (exp2 in place) + VALU l-sum
  auto packP = [&](f32x16& sv, bf16x8& fA, bf16x8& fB) {
    #pragma unroll
    for (int r = 0; r < 16; ++r) sv[r] = __builtin_amdgcn_exp2f(sv[r]);
    l_r += (((sv[0] + sv[1]) + (sv[2] + sv[3])) + ((sv[4] + sv[5]) + (sv[6] + sv[7])))
         + (((sv[8] + sv[9]) + (sv[10] + sv[11])) + ((sv[12] + sv[13]) + (sv[14] + sv[15])));
    fA = mkfrag(cvtpk(sv[0], sv[1]),  cvtpk(sv[2], sv[3]),
                cvtpk(sv[4], sv[5]),  cvtpk(sv[6], sv[7]));
    fB = mkfrag(cvtpk(sv[8], sv[9]),  cvtpk(sv[10], sv[11]),
                cvtpk(sv[12], sv[13]), cvtpk(sv[14], sv[15]));
  };
  // V A-frag group m: pos = hi*32 + m*8 + j contiguous -> single b128
  auto vfrag = [&](const char* vb, int m) -> bf16x8 {
    return *(const bf16x8*)(vb + ((l31 * 128 + hi * 64 + m * 16) ^ vswz));
  };
  auto qk = [&](const char* kb) {
    sv0 = mfma32(*(const bf16x8*)(kb + ka0), qf0, zed16);
    sv0 = mfma32(*(const bf16x8*)(kb + ka1), qf1, sv0);
    sv1 = mfma32(*(const bf16x8*)(kb + ka0 + 2048), qf0, zed16);
    sv1 = mfma32(*(const bf16x8*)(kb + ka1 + 2048), qf1, sv1);
  };

  // prologue: stage K(0), V(0), K(1); QK(0); pack(0)
  gl16(ksrc, kbuf[0] + w * 1024);
  gl16(vsrc, vbuf[0] + w * 1024);
  gl16(ksrc + BKV * HD, kbuf[1] + w * 1024);
  __syncthreads();
  qk(kbuf[0]);
  packP(sv0, pf0, pf1);
  packP(sv1, pf2, pf3);

  for (int t = 0; t < NCH; ++t) {
    const int cur = t & 1, nxt = cur ^ 1;
    const bool hn = (t + 1 < NCH);
    __syncthreads();
    // staging at chunk top: drain at next barrier sees chunk-old loads
    if (hn) gl16(vsrc + (size_t)(t + 1) * BKV, vbuf[nxt] + w * 1024);
    if (t + 2 < NCH) gl16(ksrc + (size_t)(t + 2) * BKV * HD, kbuf[cur] + w * 1024);
    // QK(t+1): writes sv (pf still holds P(t))
    if (hn) qk(kbuf[nxt]);
    // PV(t): two independent 2-chains on Ot0/Ot1
    {
      const char* vb = vbuf[cur];
      Ot0 = mfma32(vfrag(vb, 0), pf0, Ot0);
      Ot1 = mfma32(vfrag(vb, 1), pf1, Ot1);
      Ot0 = mfma32(vfrag(vb, 2), pf2, Ot0);
      Ot1 = mfma32(vfrag(vb, 3), pf3, Ot1);
    }
    // pack(t+1): overwrites pf AFTER PV(t) consumed it
    if (hn) {
      packP(sv0, pf0, pf1);
      packP(sv1, pf2, pf3);
    }
  }

  // lane holds 32 of 64 keys/chunk; partner hi^1 holds the rest
  l_r += __shfl_xor(l_r, 32, 64);

  // store unnormalized O^T partials, layout [h][sp][cg(8)][s][4] bf16
  // Ot reg r: c = (r&3) + 8*(r>>2) + 4*hi -> cg = hi + 2*(r>>2), idx = r&3
  bf16* base = accP + (size_t)(h * NSPLIT + sp) * 8 * NS * 4;
  size_t qrow = qrow0 + l31;
  #pragma unroll
  for (int m = 0; m < 4; ++m) {
    bf16x4 ov;
    #pragma unroll
    for (int j = 0; j < 4; ++j) ov[j] = (bf16)(Ot0[4 * m + j] + Ot1[4 * m + j]);
    *(bf16x4*)(base + ((size_t)(hi + 2 * m) * NS + qrow) * 4) = ov;
  }
  if (hi == 0)
    ml[(size_t)(h * NSPLIT + sp) * NS + qrow] = l_r;
}

// ---- fused combine + proj GEMM + bias + residual + mask; 32-wide s tiles ----
__global__ __launch_bounds__(256) void k_proj(
    const bf16* __restrict__ wp, const bf16* __restrict__ accP, const float* __restrict__ ml,
    const float* __restrict__ proj_b, const float* __restrict__ x,
    const float* __restrict__ mask, float* __restrict__ out) {
  int ot = blockIdx.x;            // 0..1
  int st = blockIdx.y;            // 0..191 (32-wide s tiles)
  int tid = threadIdx.x;
  __shared__ __align__(16) char at[32 * 256];   // swizzled [s][c] bf16 tile

  int s_local = tid >> 3;         // 0..31
  int s = st * 32 + s_local;
  if (ot == 0 && tid < 32)        // mask passthrough (second output)
    out[(size_t)NC * NS + st * 32 + tid] = mask[st * 32 + tid];
  #pragma unroll
  for (int i = 0; i < 2; ++i) {
    int c0 = ((tid & 7) * 2 + i) * 8;
    int h = c0 >> 5;
    float L = 0.f;
    #pragma unroll
    for (int spl = 0; spl < NSPLIT; ++spl)
      L += ml[(size_t)(h * NSPLIT + spl) * NS + s];
    float inv = 1.0f / L;
    float o[8] = {};
    int cg0 = (c0 & 31) >> 2;
    #pragma unroll
    for (int spl = 0; spl < NSPLIT; ++spl) {
      const bf16* bp = accP + ((size_t)((h * NSPLIT + spl) * 8 + cg0) * NS + s) * 4;
      bf16x4 a0 = *(const bf16x4*)(bp);
      bf16x4 a1 = *(const bf16x4*)(bp + (size_t)NS * 4);
      #pragma unroll
      for (int j = 0; j < 4; ++j) {
        o[j]     += (float)a0[j];
        o[4 + j] += (float)a1[j];
      }
    }
    bf16x8 ov;
    #pragma unroll
    for (int j = 0; j < 8; ++j) ov[j] = (bf16)(o[j] * inv);
    *(bf16x8*)(at + ((s_local * 256 + c0 * 2) ^ ((s_local & 7) << 4))) = ov;
  }
  __syncthreads();

  int w = tid >> 6, l = tid & 63;
  int lr = l & 15, lg = l >> 4;
  int o_base = ot * 64 + (w >> 1) * 32;
  int sl_base = (w & 1) * 16;
  f32x4 acc[2] = {};
  #pragma unroll
  for (int k0 = 0; k0 < NC; k0 += 32) {
    bf16x8 a[2], b;
    #pragma unroll
    for (int m = 0; m < 2; ++m)
      a[m] = *(const bf16x8*)(wp + (size_t)(o_base + m * 16 + lr) * NC + k0 + lg * 8);
    {
      int row = sl_base + lr;
      b = *(const bf16x8*)(at + ((row * 256 + (k0 + lg * 8) * 2) ^ ((row & 7) << 4)));
    }
    #pragma unroll
    for (int m = 0; m < 2; ++m)
      acc[m] = mfma16(a[m], b, acc[m]);
  }
  #pragma unroll
  for (int m = 0; m < 2; ++m)
    #pragma unroll
    for (int r = 0; r < 4; ++r) {
      int o = o_base + m * 16 + lg * 4 + r;
      int sg = st * 32 + sl_base + lr;
      float v = acc[m][r] + proj_b[o] + x[(size_t)o * NS + sg];
      out[(size_t)o * NS + sg] = v * mask[sg];
    }
}

extern "C" void kernel_launch(void* const* d_in, const int* in_sizes, int n_in,
                              void* d_out, int out_size, void* d_ws, size_t ws_size,
                              hipStream_t stream) {
  const float* x      = (const float*)d_in[0];
  const float* mask   = (const float*)d_in[1];
  const float* gn_w   = (const float*)d_in[2];
  const float* gn_b   = (const float*)d_in[3];
  const float* qkv_w  = (const float*)d_in[4];
  const float* qkv_b  = (const float*)d_in[5];
  const float* proj_w = (const float*)d_in[6];
  const float* proj_b = (const float*)d_in[7];

  char* ws = (char*)d_ws;
  float* partials = (float*)(ws + 0);            //     768 B
  float* bias_s   = (float*)(ws + 1024);         //    1536 B
  bf16*  wq       = (bf16*)(ws + 4096);          //   98304 B
  bf16*  wp       = (bf16*)(ws + 102400);        //   32768 B
  bf16*  qg       = (bf16*)(ws + 135168);        // 1.50 MB [h][s][32]
  bf16*  kg       = (bf16*)(ws + 1708032);       // 1.50 MB [h][s][32]
  bf16*  vtg      = (bf16*)(ws + 3280896);       // 1.50 MB [h][c][s] (key-permuted)
  bf16*  accP     = (bf16*)(ws + 4853760);       // 6.29 MB [h][sp][cg][s][4]
  float* ml       = (float*)(ws + 11145216);     // 393 KB  [h][sp][s]
  float* out      = (float*)d_out;

  k_prep_stats<<<288, 256, 0, stream>>>(qkv_w, qkv_b, proj_w, x, wq, wp, bias_s, partials);
  k_qkv       <<<dim3(6, 96), 256, 0, stream>>>(x, partials, gn_w, gn_b, wq, bias_s, qg, kg, vtg);
  k_attn      <<<dim3(48, 4, NSPLIT), 256, 0, stream>>>(qg, kg, vtg, accP, ml);
  k_proj      <<<dim3(2, 192), 256, 0, stream>>>(wp, accP, ml, proj_b, x, mask, out);
}

// Round 21
// 54.391 us; speedup vs baseline: 1.1165x; 1.0501x over previous
//
#include <hip/hip_runtime.h>
#include <hip/hip_bf16.h>
#include <cstddef>

typedef __bf16 bf16;
typedef __bf16 bf16x4 __attribute__((ext_vector_type(4)));
typedef __bf16 bf16x8 __attribute__((ext_vector_type(8)));
typedef float  f32x4  __attribute__((ext_vector_type(4)));
typedef float  f32x16 __attribute__((ext_vector_type(16)));

#define NC   128
#define NS   6144
#define HD   32
#define BKV  64
#define NSPLIT 4
#define NCH  ((NS / NSPLIT) / BKV)    // 24 chunks per block
#define GELEMS (16 * NS)
// 32^-0.5 * log2(e): fold attention scale AND exp->exp2 conversion into Wq
#define QK_SCALE (0.17677669529663689f * 1.4426950408889634f)

__device__ __forceinline__ f32x4 mfma16(bf16x8 a, bf16x8 b, f32x4 c) {
  return __builtin_amdgcn_mfma_f32_16x16x32_bf16(a, b, c, 0, 0, 0);
}
__device__ __forceinline__ f32x16 mfma32(bf16x8 a, bf16x8 b, f32x16 c) {
  return __builtin_amdgcn_mfma_f32_32x32x16_bf16(a, b, c, 0, 0, 0);
}
// async global->LDS, 16B per lane; LDS dest = wave-uniform base + lane*16
__device__ __forceinline__ void gl16(const bf16* g, void* s) {
  __builtin_amdgcn_global_load_lds((const __attribute__((address_space(1))) void*)g,
                                   (__attribute__((address_space(3))) void*)s, 16, 0, 0);
}
// involution swizzle: spread 16B slots (bits[4:6]) by row bits (bits[7:9])
__device__ __forceinline__ int swz(int b) { return b ^ (((b >> 7) & 7) << 4); }
__device__ __forceinline__ unsigned cvtpk(float lo, float hi) {
  unsigned r;
  asm("v_cvt_pk_bf16_f32 %0, %1, %2" : "=v"(r) : "v"(lo), "v"(hi));
  return r;
}
__device__ __forceinline__ bf16x8 mkfrag(unsigned a, unsigned b, unsigned c, unsigned d) {
  union { unsigned u[4]; bf16x8 v; } t;
  t.u[0] = a; t.u[1] = b; t.u[2] = c; t.u[3] = d;
  return t.v;
}
// V within-64-chunk key permutation for 32x32 PV path:
// key = 16m + 8jh + 4hi + b  ->  pos = hi*32 + m*8 + jh*4 + b
__device__ __forceinline__ int vperm(int k) {
  return (((k >> 2) & 1) << 5) | (((k >> 4) & 3) << 3) | (((k >> 3) & 1) << 2) | (k & 3);
}

// ---- fused: weight prep (blocks 0..191) + group-norm partial sums (192..287) ----
__global__ __launch_bounds__(256) void k_prep_stats(
    const float* __restrict__ qkv_w, const float* __restrict__ qkv_b,
    const float* __restrict__ proj_w, const float* __restrict__ x,
    bf16* __restrict__ wq, bf16* __restrict__ wp, float* __restrict__ bias_s,
    float* __restrict__ partials) {
  int bid = blockIdx.x;
  int tid = threadIdx.x;
  if (bid < 192) {
    int i = bid * 256 + tid;
    if (i < 3 * NC * NC) {
      float v = qkv_w[i];
      if (i < NC * NC) v *= QK_SCALE;
      wq[i] = (bf16)v;
    }
    if (i < NC * NC) wp[i] = (bf16)proj_w[i];
    if (i < 3 * NC) bias_s[i] = qkv_b[i] * ((i < NC) ? QK_SCALE : 1.0f);
    return;
  }
  int b = bid - 192;
  int g = b / 12, chunk = b % 12;
  float sum = 0.f, sq = 0.f;
  #pragma unroll
  for (int k = 0; k < 8; ++k) {
    int f4 = tid + k * 256;
    int c  = f4 >> 7;
    int s4 = f4 & 127;
    const float4 v = ((const float4*)x)[(size_t)(g * 16 + c) * (NS / 4) + chunk * 128 + s4];
    sum += v.x + v.y + v.z + v.w;
    sq  += v.x * v.x + v.y * v.y + v.z * v.z + v.w * v.w;
  }
  #pragma unroll
  for (int off = 32; off; off >>= 1) {
    sum += __shfl_down(sum, off, 64);
    sq  += __shfl_down(sq,  off, 64);
  }
  __shared__ float red[2][4];
  if ((tid & 63) == 0) { red[0][tid >> 6] = sum; red[1][tid >> 6] = sq; }
  __syncthreads();
  if (tid == 0) {
    partials[b * 2 + 0] = red[0][0] + red[0][1] + red[0][2] + red[0][3];
    partials[b * 2 + 1] = red[1][0] + red[1][1] + red[1][2] + red[1][3];
  }
}

// ---- fused GN-apply + QKV GEMM; epilogue via LDS transpose -> coalesced stores ----
// outputs: qg,kg [h][s][32]; v transposed vtg [h][c][s] with key perm (vperm)
__global__ __launch_bounds__(256) void k_qkv(
    const float* __restrict__ x, const float* __restrict__ partials,
    const float* __restrict__ gn_w, const float* __restrict__ gn_b,
    const bf16* __restrict__ wq, const float* __restrict__ bias_s,
    bf16* __restrict__ qg, bf16* __restrict__ kg, bf16* __restrict__ vtg) {
  int ot = blockIdx.x;            // 0..5
  int st = blockIdx.y;            // 0..95
  int tid = threadIdx.x;
  __shared__ __align__(16) char xn[64 * 256];   // swizzled [s][c] input tile; reused by epilogue
  __shared__ float swc[NC], sbc[NC];

  if (tid < NC) {
    int g = tid >> 4;
    float sum = 0.f, sq = 0.f;
    #pragma unroll
    for (int i = 0; i < 12; ++i) {
      sum += partials[(g * 12 + i) * 2 + 0];
      sq  += partials[(g * 12 + i) * 2 + 1];
    }
    float mean = sum * (1.0f / GELEMS);
    float var  = sq  * (1.0f / GELEMS) - mean * mean;
    float rstd = rsqrtf(var + 1e-5f);
    float wc = gn_w[tid] * rstd;
    swc[tid] = wc;
    sbc[tid] = gn_b[tid] - mean * wc;
  }
  __syncthreads();

  int s_local = tid & 63;
  int s_glob  = st * 64 + s_local;
  int wk = tid >> 6;
  #pragma unroll
  for (int i = 0; i < 4; ++i) {
    int c0 = (wk * 4 + i) * 8;
    bf16x8 ov;
    #pragma unroll
    for (int j = 0; j < 8; ++j) {
      int c = c0 + j;
      ov[j] = (bf16)(x[(size_t)c * NS + s_glob] * swc[c] + sbc[c]);
    }
    *(bf16x8*)(xn + ((s_local * 256 + c0 * 2) ^ ((s_local & 7) << 4))) = ov;
  }
  __syncthreads();

  int w = tid >> 6, l = tid & 63;
  int lr = l & 15, lg = l >> 4;
  int o_base = ot * 64 + (w >> 1) * 32;
  int sl_base = (w & 1) * 32;
  f32x4 acc[2][2] = {};
  #pragma unroll
  for (int k0 = 0; k0 < NC; k0 += 32) {
    bf16x8 a[2], b[2];
    #pragma unroll
    for (int m = 0; m < 2; ++m)
      a[m] = *(const bf16x8*)(wq + (size_t)(o_base + m * 16 + lr) * NC + k0 + lg * 8);
    #pragma unroll
    for (int n = 0; n < 2; ++n) {
      int row = sl_base + n * 16 + lr;
      b[n] = *(const bf16x8*)(xn + ((row * 256 + (k0 + lg * 8) * 2) ^ ((row & 7) << 4)));
    }
    #pragma unroll
    for (int m = 0; m < 2; ++m)
      #pragma unroll
      for (int n = 0; n < 2; ++n)
        acc[m][n] = mfma16(a[m], b[n], acc[m][n]);
  }

  // ---- epilogue: stage tile in LDS (pitch 72 bf16), then coalesced stores ----
  __syncthreads();                 // xn reads done; reuse as out tile
  bf16* ot_lds = (bf16*)xn;        // q/k: [s_local][o_local]; v: [c_local][pos]
  const bool is_v = (ot >= 4);
  #pragma unroll
  for (int m = 0; m < 2; ++m)
    #pragma unroll
    for (int n = 0; n < 2; ++n)
      #pragma unroll
      for (int r = 0; r < 4; ++r) {
        int o_l = (w >> 1) * 32 + m * 16 + lg * 4 + r;
        int s_l = (w & 1) * 32 + n * 16 + lr;
        int o = ot * 64 + o_l;
        bf16 v = (bf16)(acc[m][n][r] + bias_s[o]);
        if (is_v) ot_lds[o_l * 72 + vperm(s_l)] = v;   // [c][pos]
        else      ot_lds[s_l * 72 + o_l]        = v;   // [s][o]
      }
  __syncthreads();

  if (!is_v) {
    bf16* dst = (ot < 2) ? qg : kg;
    int head0 = (ot & 1) * 2;
    int c8 = tid & 3, s_l = tid >> 2;
    size_t s = (size_t)st * 64 + s_l;
    #pragma unroll
    for (int i = 0; i < 2; ++i) {
      bf16x8 v = *(const bf16x8*)(ot_lds + s_l * 72 + i * 32 + c8 * 8);
      *(bf16x8*)(dst + ((size_t)(head0 + i) * NS + s) * HD + c8 * 8) = v;
    }
  } else {
    int head0 = (ot - 4) * 2;
    int c_l = tid >> 2;
    int head = head0 + (c_l >> 5), c32 = c_l & 31;
    bf16* drow = vtg + ((size_t)head * HD + c32) * NS + st * 64;
    #pragma unroll
    for (int i = 0; i < 2; ++i) {
      int pos8 = (tid & 3) * 2 + i;
      bf16x8 v = *(const bf16x8*)(ot_lds + c_l * 72 + pos8 * 8);
      *(bf16x8*)(drow + pos8 * 8) = v;
    }
  }
}

// ---- flash attention: 32x32 MFMA (32 q-rows/wave), fixed-m softmax, K/V
//      LDS-staged, P IN REGISTERS (permuted keys), V pre-permuted -> 1 b128/frag ----
__global__ __launch_bounds__(256, 4) void k_attn(
    const bf16* __restrict__ qg, const bf16* __restrict__ kg, const bf16* __restrict__ vtg,
    bf16* __restrict__ accP, float* __restrict__ ml) {
  const int h = blockIdx.y, sp = blockIdx.z;
  const int tid = threadIdx.x;
  const int w = tid >> 6, l = tid & 63;
  const int l31 = l & 31, hi = l >> 5;
  const int qrow0 = blockIdx.x * 128 + w * 32;

  __shared__ __align__(16) char kbuf[2][4096];   // K chunk [64 key][32 c], swizzled
  __shared__ __align__(16) char vbuf[2][4096];   // V^T chunk [32 c][64 pos], swizzled
  const int kswz = ((l31 >> 1) & 7) << 4;
  const int vswz = (l31 & 7) << 4;
  const int ka0  = (l31 * 64 + hi * 16) ^ kswz;        // kt0 c-slice0 (+2048: kt1)
  const int ka1  = (l31 * 64 + 32 + hi * 16) ^ kswz;   // kt0 c-slice1

  const bf16* qp = qg + (size_t)h * NS * HD;
  const bf16* kp = kg + (size_t)h * NS * HD;
  const bf16* vp = vtg + (size_t)h * HD * NS;

  // Q as B of mfma32(K,Q): lane holds Q[qrow0+l31][slice*16 + hi*8 + j]
  bf16x8 qf0 = *(const bf16x8*)(qp + (size_t)(qrow0 + l31) * HD + hi * 8);
  bf16x8 qf1 = *(const bf16x8*)(qp + (size_t)(qrow0 + l31) * HD + 16 + hi * 8);

  f32x16 Ot = {};                      // O^T: col q = l31, rows c; never rescaled
  float l_r = 0.f;                     // per-lane l partial (this lane's 32 keys/chunk)
  const f32x16 zed16 = {};
  const int kv_beg = sp * (NS / NSPLIT);

  // staging source mapping (pre-swizzled involution, validated R5-R18)
  const int o_st = w * 1024 + (l << 4);
  const int u_st = swz(o_st);
  const bf16* ksrc = kp + (size_t)(kv_beg + (u_st >> 6)) * HD + ((u_st & 63) >> 1);
  const bf16* vsrc = vp + (size_t)(u_st >> 7) * NS + kv_beg + ((u_st & 127) >> 1);

  f32x16 sv0, sv1;
  bf16x8 pf0, pf1, pf2, pf3;  // P^T B-frags; group m keys: 16m + 8(j>>2)+4hi+(j&3)

  // fixed-m softmax + in-register pack + VALU l-sum
  auto packP = [&](f32x16& sv, bf16x8& fA, bf16x8& fB) {
    float e[16];
    #pragma unroll
    for (int r = 0; r < 16; ++r) e[r] = __builtin_amdgcn_exp2f(sv[r]);
    l_r += (((e[0] + e[1]) + (e[2] + e[3])) + ((e[4] + e[5]) + (e[6] + e[7])))
         + (((e[8] + e[9]) + (e[10] + e[11])) + ((e[12] + e[13]) + (e[14] + e[15])));
    fA = mkfrag(cvtpk(e[0], e[1]),  cvtpk(e[2], e[3]),
                cvtpk(e[4], e[5]),  cvtpk(e[6], e[7]));
    fB = mkfrag(cvtpk(e[8], e[9]),  cvtpk(e[10], e[11]),
                cvtpk(e[12], e[13]), cvtpk(e[14], e[15]));
  };
  // V A-frag group m: pos = hi*32 + m*8 + j contiguous -> single b128
  auto vfrag = [&](const char* vb, int m) -> bf16x8 {
    return *(const bf16x8*)(vb + ((l31 * 128 + hi * 64 + m * 16) ^ vswz));
  };
  auto qk = [&](const char* kb) {
    sv0 = mfma32(*(const bf16x8*)(kb + ka0), qf0, zed16);
    sv0 = mfma32(*(const bf16x8*)(kb + ka1), qf1, sv0);
    sv1 = mfma32(*(const bf16x8*)(kb + ka0 + 2048), qf0, zed16);
    sv1 = mfma32(*(const bf16x8*)(kb + ka1 + 2048), qf1, sv1);
  };

  // prologue: stage K(0), V(0), K(1); QK(0); pack(0)
  gl16(ksrc, kbuf[0] + w * 1024);
  gl16(vsrc, vbuf[0] + w * 1024);
  gl16(ksrc + BKV * HD, kbuf[1] + w * 1024);
  __syncthreads();
  qk(kbuf[0]);
  packP(sv0, pf0, pf1);
  packP(sv1, pf2, pf3);

  for (int t = 0; t < NCH; ++t) {
    const int cur = t & 1, nxt = cur ^ 1;
    const bool hn = (t + 1 < NCH);
    __syncthreads();
    // staging at chunk top: drain at next barrier sees chunk-old loads
    if (hn) gl16(vsrc + (size_t)(t + 1) * BKV, vbuf[nxt] + w * 1024);
    if (t + 2 < NCH) gl16(ksrc + (size_t)(t + 2) * BKV * HD, kbuf[cur] + w * 1024);
    // QK(t+1): writes sv (pf still holds P(t))
    if (hn) qk(kbuf[nxt]);
    // PV(t): P(t) from registers, V(t) from vbuf[cur]
    {
      const char* vb = vbuf[cur];
      Ot = mfma32(vfrag(vb, 0), pf0, Ot);
      Ot = mfma32(vfrag(vb, 1), pf1, Ot);
      Ot = mfma32(vfrag(vb, 2), pf2, Ot);
      Ot = mfma32(vfrag(vb, 3), pf3, Ot);
    }
    // pack(t+1): overwrites pf AFTER PV(t) consumed it
    if (hn) {
      packP(sv0, pf0, pf1);
      packP(sv1, pf2, pf3);
    }
  }

  // lane holds 32 of 64 keys/chunk; partner hi^1 holds the rest
  l_r += __shfl_xor(l_r, 32, 64);

  // store unnormalized O^T partials, layout [h][sp][cg(8)][s][4] bf16
  // Ot reg r: c = (r&3) + 8*(r>>2) + 4*hi -> cg = hi + 2*(r>>2), idx = r&3
  bf16* base = accP + (size_t)(h * NSPLIT + sp) * 8 * NS * 4;
  size_t qrow = qrow0 + l31;
  #pragma unroll
  for (int m = 0; m < 4; ++m) {
    bf16x4 ov;
    #pragma unroll
    for (int j = 0; j < 4; ++j) ov[j] = (bf16)Ot[4 * m + j];
    *(bf16x4*)(base + ((size_t)(hi + 2 * m) * NS + qrow) * 4) = ov;
  }
  if (hi == 0)
    ml[(size_t)(h * NSPLIT + sp) * NS + qrow] = l_r;
}

// ---- fused combine + proj GEMM + bias + residual + mask; 32-wide s tiles ----
__global__ __launch_bounds__(256) void k_proj(
    const bf16* __restrict__ wp, const bf16* __restrict__ accP, const float* __restrict__ ml,
    const float* __restrict__ proj_b, const float* __restrict__ x,
    const float* __restrict__ mask, float* __restrict__ out) {
  int ot = blockIdx.x;            // 0..1
  int st = blockIdx.y;            // 0..191 (32-wide s tiles)
  int tid = threadIdx.x;
  __shared__ __align__(16) char at[32 * 256];   // swizzled [s][c] bf16 tile

  int s_local = tid >> 3;         // 0..31
  int s = st * 32 + s_local;
  if (ot == 0 && tid < 32)        // mask passthrough (second output)
    out[(size_t)NC * NS + st * 32 + tid] = mask[st * 32 + tid];
  #pragma unroll
  for (int i = 0; i < 2; ++i) {
    int c0 = ((tid & 7) * 2 + i) * 8;
    int h = c0 >> 5;
    float L = 0.f;
    #pragma unroll
    for (int spl = 0; spl < NSPLIT; ++spl)
      L += ml[(size_t)(h * NSPLIT + spl) * NS + s];
    float inv = 1.0f / L;
    float o[8] = {};
    int cg0 = (c0 & 31) >> 2;
    #pragma unroll
    for (int spl = 0; spl < NSPLIT; ++spl) {
      const bf16* bp = accP + ((size_t)((h * NSPLIT + spl) * 8 + cg0) * NS + s) * 4;
      bf16x4 a0 = *(const bf16x4*)(bp);
      bf16x4 a1 = *(const bf16x4*)(bp + (size_t)NS * 4);
      #pragma unroll
      for (int j = 0; j < 4; ++j) {
        o[j]     += (float)a0[j];
        o[4 + j] += (float)a1[j];
      }
    }
    bf16x8 ov;
    #pragma unroll
    for (int j = 0; j < 8; ++j) ov[j] = (bf16)(o[j] * inv);
    *(bf16x8*)(at + ((s_local * 256 + c0 * 2) ^ ((s_local & 7) << 4))) = ov;
  }
  __syncthreads();

  int w = tid >> 6, l = tid & 63;
  int lr = l & 15, lg = l >> 4;
  int o_base = ot * 64 + (w >> 1) * 32;
  int sl_base = (w & 1) * 16;
  f32x4 acc[2] = {};
  #pragma unroll
  for (int k0 = 0; k0 < NC; k0 += 32) {
    bf16x8 a[2], b;
    #pragma unroll
    for (int m = 0; m < 2; ++m)
      a[m] = *(const bf16x8*)(wp + (size_t)(o_base + m * 16 + lr) * NC + k0 + lg * 8);
    {
      int row = sl_base + lr;
      b = *(const bf16x8*)(at + ((row * 256 + (k0 + lg * 8) * 2) ^ ((row & 7) << 4)));
    }
    #pragma unroll
    for (int m = 0; m < 2; ++m)
      acc[m] = mfma16(a[m], b, acc[m]);
  }
  #pragma unroll
  for (int m = 0; m < 2; ++m)
    #pragma unroll
    for (int r = 0; r < 4; ++r) {
      int o = o_base + m * 16 + lg * 4 + r;
      int sg = st * 32 + sl_base + lr;
      float v = acc[m][r] + proj_b[o] + x[(size_t)o * NS + sg];
      out[(size_t)o * NS + sg] = v * mask[sg];
    }
}

extern "C" void kernel_launch(void* const* d_in, const int* in_sizes, int n_in,
                              void* d_out, int out_size, void* d_ws, size_t ws_size,
                              hipStream_t stream) {
  const float* x      = (const float*)d_in[0];
  const float* mask   = (const float*)d_in[1];
  const float* gn_w   = (const float*)d_in[2];
  const float* gn_b   = (const float*)d_in[3];
  const float* qkv_w  = (const float*)d_in[4];
  const float* qkv_b  = (const float*)d_in[5];
  const float* proj_w = (const float*)d_in[6];
  const float* proj_b = (const float*)d_in[7];

  char* ws = (char*)d_ws;
  float* partials = (float*)(ws + 0);            //     768 B
  float* bias_s   = (float*)(ws + 1024);         //    1536 B
  bf16*  wq       = (bf16*)(ws + 4096);          //   98304 B
  bf16*  wp       = (bf16*)(ws + 102400);        //   32768 B
  bf16*  qg       = (bf16*)(ws + 135168);        // 1.50 MB [h][s][32]
  bf16*  kg       = (bf16*)(ws + 1708032);       // 1.50 MB [h][s][32]
  bf16*  vtg      = (bf16*)(ws + 3280896);       // 1.50 MB [h][c][s] (key-permuted)
  bf16*  accP     = (bf16*)(ws + 4853760);       // 6.29 MB [h][sp][cg][s][4]
  float* ml       = (float*)(ws + 11145216);     // 393 KB  [h][sp][s]
  float* out      = (float*)d_out;

  k_prep_stats<<<288, 256, 0, stream>>>(qkv_w, qkv_b, proj_w, x, wq, wp, bias_s, partials);
  k_qkv       <<<dim3(6, 96), 256, 0, stream>>>(x, partials, gn_w, gn_b, wq, bias_s, qg, kg, vtg);
  k_attn      <<<dim3(48, 4, NSPLIT), 256, 0, stream>>>(qg, kg, vtg, accP, ml);
  k_proj      <<<dim3(2, 192), 256, 0, stream>>>(wp, accP, ml, proj_b, x, mask, out);
}

// Round 22
// 53.762 us; speedup vs baseline: 1.1295x; 1.0117x over previous
//
#include <hip/hip_runtime.h>
#include <hip/hip_bf16.h>
#include <cstddef>

typedef __bf16 bf16;
typedef __bf16 bf16x4 __attribute__((ext_vector_type(4)));
typedef __bf16 bf16x8 __attribute__((ext_vector_type(8)));
typedef float  f32x4  __attribute__((ext_vector_type(4)));
typedef float  f32x16 __attribute__((ext_vector_type(16)));

#define NC   128
#define NS   6144
#define HD   32
#define BKV  128
#define NSPLIT 4
#define NCH  ((NS / NSPLIT) / BKV)    // 12 chunks per block (128 keys each)
#define GELEMS (16 * NS)
// 32^-0.5 * log2(e): fold attention scale AND exp->exp2 conversion into Wq
#define QK_SCALE (0.17677669529663689f * 1.4426950408889634f)

__device__ __forceinline__ f32x4 mfma16(bf16x8 a, bf16x8 b, f32x4 c) {
  return __builtin_amdgcn_mfma_f32_16x16x32_bf16(a, b, c, 0, 0, 0);
}
__device__ __forceinline__ f32x16 mfma32(bf16x8 a, bf16x8 b, f32x16 c) {
  return __builtin_amdgcn_mfma_f32_32x32x16_bf16(a, b, c, 0, 0, 0);
}
// async global->LDS, 16B per lane; LDS dest = wave-uniform base + lane*16
__device__ __forceinline__ void gl16(const bf16* g, void* s) {
  __builtin_amdgcn_global_load_lds((const __attribute__((address_space(1))) void*)g,
                                   (__attribute__((address_space(3))) void*)s, 16, 0, 0);
}
// involution swizzle: spread 16B slots (bits[4:6]) by row bits (bits[7:9])
__device__ __forceinline__ int swz(int b) { return b ^ (((b >> 7) & 7) << 4); }
__device__ __forceinline__ unsigned cvtpk(float lo, float hi) {
  unsigned r;
  asm("v_cvt_pk_bf16_f32 %0, %1, %2" : "=v"(r) : "v"(lo), "v"(hi));
  return r;
}
__device__ __forceinline__ bf16x8 mkfrag(unsigned a, unsigned b, unsigned c, unsigned d) {
  union { unsigned u[4]; bf16x8 v; } t;
  t.u[0] = a; t.u[1] = b; t.u[2] = c; t.u[3] = d;
  return t.v;
}
// V within-64-key-group permutation for 32x32 PV path:
// key = 16m + 8jh + 4hi + b  ->  pos = hi*32 + m*8 + jh*4 + b
__device__ __forceinline__ int vperm(int k) {
  return (((k >> 2) & 1) << 5) | (((k >> 4) & 3) << 3) | (((k >> 3) & 1) << 2) | (k & 3);
}

// ---- fused: weight prep (blocks 0..191) + group-norm partial sums (192..287) ----
__global__ __launch_bounds__(256) void k_prep_stats(
    const float* __restrict__ qkv_w, const float* __restrict__ qkv_b,
    const float* __restrict__ proj_w, const float* __restrict__ x,
    bf16* __restrict__ wq, bf16* __restrict__ wp, float* __restrict__ bias_s,
    float* __restrict__ partials) {
  int bid = blockIdx.x;
  int tid = threadIdx.x;
  if (bid < 192) {
    int i = bid * 256 + tid;
    if (i < 3 * NC * NC) {
      float v = qkv_w[i];
      if (i < NC * NC) v *= QK_SCALE;
      wq[i] = (bf16)v;
    }
    if (i < NC * NC) wp[i] = (bf16)proj_w[i];
    if (i < 3 * NC) bias_s[i] = qkv_b[i] * ((i < NC) ? QK_SCALE : 1.0f);
    return;
  }
  int b = bid - 192;
  int g = b / 12, chunk = b % 12;
  float sum = 0.f, sq = 0.f;
  #pragma unroll
  for (int k = 0; k < 8; ++k) {
    int f4 = tid + k * 256;
    int c  = f4 >> 7;
    int s4 = f4 & 127;
    const float4 v = ((const float4*)x)[(size_t)(g * 16 + c) * (NS / 4) + chunk * 128 + s4];
    sum += v.x + v.y + v.z + v.w;
    sq  += v.x * v.x + v.y * v.y + v.z * v.z + v.w * v.w;
  }
  #pragma unroll
  for (int off = 32; off; off >>= 1) {
    sum += __shfl_down(sum, off, 64);
    sq  += __shfl_down(sq,  off, 64);
  }
  __shared__ float red[2][4];
  if ((tid & 63) == 0) { red[0][tid >> 6] = sum; red[1][tid >> 6] = sq; }
  __syncthreads();
  if (tid == 0) {
    partials[b * 2 + 0] = red[0][0] + red[0][1] + red[0][2] + red[0][3];
    partials[b * 2 + 1] = red[1][0] + red[1][1] + red[1][2] + red[1][3];
  }
}

// ---- fused GN-apply + QKV GEMM; epilogue via LDS transpose -> coalesced stores ----
// outputs: qg,kg [h][s][32]; v transposed vtg [h][c][s] with key perm (vperm)
__global__ __launch_bounds__(256) void k_qkv(
    const float* __restrict__ x, const float* __restrict__ partials,
    const float* __restrict__ gn_w, const float* __restrict__ gn_b,
    const bf16* __restrict__ wq, const float* __restrict__ bias_s,
    bf16* __restrict__ qg, bf16* __restrict__ kg, bf16* __restrict__ vtg) {
  int ot = blockIdx.x;            // 0..5
  int st = blockIdx.y;            // 0..95
  int tid = threadIdx.x;
  __shared__ __align__(16) char xn[64 * 256];   // swizzled [s][c] input tile; reused by epilogue
  __shared__ float swc[NC], sbc[NC];

  if (tid < NC) {
    int g = tid >> 4;
    float sum = 0.f, sq = 0.f;
    #pragma unroll
    for (int i = 0; i < 12; ++i) {
      sum += partials[(g * 12 + i) * 2 + 0];
      sq  += partials[(g * 12 + i) * 2 + 1];
    }
    float mean = sum * (1.0f / GELEMS);
    float var  = sq  * (1.0f / GELEMS) - mean * mean;
    float rstd = rsqrtf(var + 1e-5f);
    float wc = gn_w[tid] * rstd;
    swc[tid] = wc;
    sbc[tid] = gn_b[tid] - mean * wc;
  }
  __syncthreads();

  int s_local = tid & 63;
  int s_glob  = st * 64 + s_local;
  int wk = tid >> 6;
  #pragma unroll
  for (int i = 0; i < 4; ++i) {
    int c0 = (wk * 4 + i) * 8;
    bf16x8 ov;
    #pragma unroll
    for (int j = 0; j < 8; ++j) {
      int c = c0 + j;
      ov[j] = (bf16)(x[(size_t)c * NS + s_glob] * swc[c] + sbc[c]);
    }
    *(bf16x8*)(xn + ((s_local * 256 + c0 * 2) ^ ((s_local & 7) << 4))) = ov;
  }
  __syncthreads();

  int w = tid >> 6, l = tid & 63;
  int lr = l & 15, lg = l >> 4;
  int o_base = ot * 64 + (w >> 1) * 32;
  int sl_base = (w & 1) * 32;
  f32x4 acc[2][2] = {};
  #pragma unroll
  for (int k0 = 0; k0 < NC; k0 += 32) {
    bf16x8 a[2], b[2];
    #pragma unroll
    for (int m = 0; m < 2; ++m)
      a[m] = *(const bf16x8*)(wq + (size_t)(o_base + m * 16 + lr) * NC + k0 + lg * 8);
    #pragma unroll
    for (int n = 0; n < 2; ++n) {
      int row = sl_base + n * 16 + lr;
      b[n] = *(const bf16x8*)(xn + ((row * 256 + (k0 + lg * 8) * 2) ^ ((row & 7) << 4)));
    }
    #pragma unroll
    for (int m = 0; m < 2; ++m)
      #pragma unroll
      for (int n = 0; n < 2; ++n)
        acc[m][n] = mfma16(a[m], b[n], acc[m][n]);
  }

  // ---- epilogue: stage tile in LDS (pitch 72 bf16), then coalesced stores ----
  __syncthreads();                 // xn reads done; reuse as out tile
  bf16* ot_lds = (bf16*)xn;        // q/k: [s_local][o_local]; v: [c_local][pos]
  const bool is_v = (ot >= 4);
  #pragma unroll
  for (int m = 0; m < 2; ++m)
    #pragma unroll
    for (int n = 0; n < 2; ++n)
      #pragma unroll
      for (int r = 0; r < 4; ++r) {
        int o_l = (w >> 1) * 32 + m * 16 + lg * 4 + r;
        int s_l = (w & 1) * 32 + n * 16 + lr;
        int o = ot * 64 + o_l;
        bf16 v = (bf16)(acc[m][n][r] + bias_s[o]);
        if (is_v) ot_lds[o_l * 72 + vperm(s_l)] = v;   // [c][pos]
        else      ot_lds[s_l * 72 + o_l]        = v;   // [s][o]
      }
  __syncthreads();

  if (!is_v) {
    bf16* dst = (ot < 2) ? qg : kg;
    int head0 = (ot & 1) * 2;
    int c8 = tid & 3, s_l = tid >> 2;
    size_t s = (size_t)st * 64 + s_l;
    #pragma unroll
    for (int i = 0; i < 2; ++i) {
      bf16x8 v = *(const bf16x8*)(ot_lds + s_l * 72 + i * 32 + c8 * 8);
      *(bf16x8*)(dst + ((size_t)(head0 + i) * NS + s) * HD + c8 * 8) = v;
    }
  } else {
    int head0 = (ot - 4) * 2;
    int c_l = tid >> 2;
    int head = head0 + (c_l >> 5), c32 = c_l & 31;
    bf16* drow = vtg + ((size_t)head * HD + c32) * NS + st * 64;
    #pragma unroll
    for (int i = 0; i < 2; ++i) {
      int pos8 = (tid & 3) * 2 + i;
      bf16x8 v = *(const bf16x8*)(ot_lds + c_l * 72 + pos8 * 8);
      *(bf16x8*)(drow + pos8 * 8) = v;
    }
  }
}

// ---- flash attention: 32x32 MFMA, fixed-m softmax, in-register P (permuted
//      keys), V pre-permuted -> 1 b128/frag; BKV=128 as two 4KB panels ->
//      HALF the barriers (12/block); per-half pf sets pA/pB pipeline halves ----
__global__ __launch_bounds__(256, 4) void k_attn(
    const bf16* __restrict__ qg, const bf16* __restrict__ kg, const bf16* __restrict__ vtg,
    bf16* __restrict__ accP, float* __restrict__ ml) {
  const int h = blockIdx.y, sp = blockIdx.z;
  const int tid = threadIdx.x;
  const int w = tid >> 6, l = tid & 63;
  const int l31 = l & 31, hi = l >> 5;
  const int qrow0 = blockIdx.x * 128 + w * 32;

  __shared__ __align__(16) char kbuf[2][8192];   // 2 panels of K [64 key][32 c]
  __shared__ __align__(16) char vbuf[2][8192];   // 2 panels of V^T [32 c][64 pos]
  const int kswz = ((l31 >> 1) & 7) << 4;
  const int vswz = (l31 & 7) << 4;
  const int ka0  = (l31 * 64 + hi * 16) ^ kswz;        // panel-local, +2048: kt1
  const int ka1  = (l31 * 64 + 32 + hi * 16) ^ kswz;

  const bf16* qp = qg + (size_t)h * NS * HD;
  const bf16* kp = kg + (size_t)h * NS * HD;
  const bf16* vp = vtg + (size_t)h * HD * NS;

  // Q as B of mfma32(K,Q): lane holds Q[qrow0+l31][slice*16 + hi*8 + j]
  bf16x8 qf0 = *(const bf16x8*)(qp + (size_t)(qrow0 + l31) * HD + hi * 8);
  bf16x8 qf1 = *(const bf16x8*)(qp + (size_t)(qrow0 + l31) * HD + 16 + hi * 8);

  f32x16 Ot = {};                      // O^T: col q = l31, rows c; never rescaled
  float l_r = 0.f;
  const f32x16 zed16 = {};
  const int kv_beg = sp * (NS / NSPLIT);

  // staging source mapping per 4KB panel (pre-swizzled involution, R5-R21)
  const int o_st = w * 1024 + (l << 4);
  const int u_st = swz(o_st);
  const bf16* ksrc = kp + (size_t)(kv_beg + (u_st >> 6)) * HD + ((u_st & 63) >> 1);
  const bf16* vsrc = vp + (size_t)(u_st >> 7) * NS + kv_beg + ((u_st & 127) >> 1);

  f32x16 sv0, sv1;
  bf16x8 pA0, pA1, pA2, pA3;  // P^T frags, half0 (keys chunk*128 + 0..63)
  bf16x8 pB0, pB1, pB2, pB3;  // P^T frags, half1 (keys chunk*128 + 64..127)

  // fixed-m softmax + in-register pack + VALU l-sum
  auto packP = [&](f32x16& sv, bf16x8& fA, bf16x8& fB) {
    float e[16];
    #pragma unroll
    for (int r = 0; r < 16; ++r) e[r] = __builtin_amdgcn_exp2f(sv[r]);
    l_r += (((e[0] + e[1]) + (e[2] + e[3])) + ((e[4] + e[5]) + (e[6] + e[7])))
         + (((e[8] + e[9]) + (e[10] + e[11])) + ((e[12] + e[13]) + (e[14] + e[15])));
    fA = mkfrag(cvtpk(e[0], e[1]),  cvtpk(e[2], e[3]),
                cvtpk(e[4], e[5]),  cvtpk(e[6], e[7]));
    fB = mkfrag(cvtpk(e[8], e[9]),  cvtpk(e[10], e[11]),
                cvtpk(e[12], e[13]), cvtpk(e[14], e[15]));
  };
  // V A-frag group m within a panel: pos = hi*32 + m*8 + j -> single b128
  auto vfrag = [&](const char* vb, int m) -> bf16x8 {
    return *(const bf16x8*)(vb + ((l31 * 128 + hi * 64 + m * 16) ^ vswz));
  };
  auto qk = [&](const char* kb) {   // one 64-key panel -> sv0, sv1
    sv0 = mfma32(*(const bf16x8*)(kb + ka0), qf0, zed16);
    sv0 = mfma32(*(const bf16x8*)(kb + ka1), qf1, sv0);
    sv1 = mfma32(*(const bf16x8*)(kb + ka0 + 2048), qf0, zed16);
    sv1 = mfma32(*(const bf16x8*)(kb + ka1 + 2048), qf1, sv1);
  };

  // prologue: stage K(0) p0+p1, V(0) p0+p1, K(1) p0+p1; QK(0) both halves
  gl16(ksrc,               kbuf[0] + w * 1024);
  gl16(ksrc + 64 * HD,     kbuf[0] + 4096 + w * 1024);
  gl16(vsrc,               vbuf[0] + w * 1024);
  gl16(vsrc + 64,          vbuf[0] + 4096 + w * 1024);
  gl16(ksrc + 128 * HD,    kbuf[1] + w * 1024);
  gl16(ksrc + 192 * HD,    kbuf[1] + 4096 + w * 1024);
  __syncthreads();
  qk(kbuf[0]);
  packP(sv0, pA0, pA1);
  packP(sv1, pA2, pA3);
  qk(kbuf[0] + 4096);
  packP(sv0, pB0, pB1);
  packP(sv1, pB2, pB3);

  for (int t = 0; t < NCH; ++t) {
    const int cur = t & 1, nxt = cur ^ 1;
    const bool hn = (t + 1 < NCH);
    __syncthreads();
    // staging at chunk top: drain at next barrier sees chunk-old loads.
    // vbuf[nxt] last read: PV(t-1) (pre-barrier); kbuf[cur] last read: QK(t)
    // issued last iteration (pre-barrier).
    if (hn) {
      gl16(vsrc + (size_t)(t + 1) * BKV,      vbuf[nxt] + w * 1024);
      gl16(vsrc + (size_t)(t + 1) * BKV + 64, vbuf[nxt] + 4096 + w * 1024);
    }
    if (t + 2 < NCH) {
      gl16(ksrc + (size_t)(t + 2) * BKV * HD,        kbuf[cur] + w * 1024);
      gl16(ksrc + ((size_t)(t + 2) * BKV + 64) * HD, kbuf[cur] + 4096 + w * 1024);
    }
    // half0: QK(t+1,h0) || PV(t,h0); then pack(t+1,h0)
    if (hn) qk(kbuf[nxt]);
    {
      const char* vb = vbuf[cur];
      Ot = mfma32(vfrag(vb, 0), pA0, Ot);
      Ot = mfma32(vfrag(vb, 1), pA1, Ot);
      Ot = mfma32(vfrag(vb, 2), pA2, Ot);
      Ot = mfma32(vfrag(vb, 3), pA3, Ot);
    }
    if (hn) {
      packP(sv0, pA0, pA1);
      packP(sv1, pA2, pA3);
    }
    // half1: QK(t+1,h1) || PV(t,h1); then pack(t+1,h1)
    if (hn) qk(kbuf[nxt] + 4096);
    {
      const char* vb = vbuf[cur] + 4096;
      Ot = mfma32(vfrag(vb, 0), pB0, Ot);
      Ot = mfma32(vfrag(vb, 1), pB1, Ot);
      Ot = mfma32(vfrag(vb, 2), pB2, Ot);
      Ot = mfma32(vfrag(vb, 3), pB3, Ot);
    }
    if (hn) {
      packP(sv0, pB0, pB1);
      packP(sv1, pB2, pB3);
    }
  }

  // lane holds 64 of 128 keys/chunk; partner hi^1 holds the rest
  l_r += __shfl_xor(l_r, 32, 64);

  // store unnormalized O^T partials, layout [h][sp][cg(8)][s][4] bf16
  // Ot reg r: c = (r&3) + 8*(r>>2) + 4*hi -> cg = hi + 2*(r>>2), idx = r&3
  bf16* base = accP + (size_t)(h * NSPLIT + sp) * 8 * NS * 4;
  size_t qrow = qrow0 + l31;
  #pragma unroll
  for (int m = 0; m < 4; ++m) {
    bf16x4 ov;
    #pragma unroll
    for (int j = 0; j < 4; ++j) ov[j] = (bf16)Ot[4 * m + j];
    *(bf16x4*)(base + ((size_t)(hi + 2 * m) * NS + qrow) * 4) = ov;
  }
  if (hi == 0)
    ml[(size_t)(h * NSPLIT + sp) * NS + qrow] = l_r;
}

// ---- fused combine + proj GEMM + bias + residual + mask; 32-wide s tiles ----
__global__ __launch_bounds__(256) void k_proj(
    const bf16* __restrict__ wp, const bf16* __restrict__ accP, const float* __restrict__ ml,
    const float* __restrict__ proj_b, const float* __restrict__ x,
    const float* __restrict__ mask, float* __restrict__ out) {
  int ot = blockIdx.x;            // 0..1
  int st = blockIdx.y;            // 0..191 (32-wide s tiles)
  int tid = threadIdx.x;
  __shared__ __align__(16) char at[32 * 256];   // swizzled [s][c] bf16 tile

  int s_local = tid >> 3;         // 0..31
  int s = st * 32 + s_local;
  if (ot == 0 && tid < 32)        // mask passthrough (second output)
    out[(size_t)NC * NS + st * 32 + tid] = mask[st * 32 + tid];
  #pragma unroll
  for (int i = 0; i < 2; ++i) {
    int c0 = ((tid & 7) * 2 + i) * 8;
    int h = c0 >> 5;
    float L = 0.f;
    #pragma unroll
    for (int spl = 0; spl < NSPLIT; ++spl)
      L += ml[(size_t)(h * NSPLIT + spl) * NS + s];
    float inv = 1.0f / L;
    float o[8] = {};
    int cg0 = (c0 & 31) >> 2;
    #pragma unroll
    for (int spl = 0; spl < NSPLIT; ++spl) {
      const bf16* bp = accP + ((size_t)((h * NSPLIT + spl) * 8 + cg0) * NS + s) * 4;
      bf16x4 a0 = *(const bf16x4*)(bp);
      bf16x4 a1 = *(const bf16x4*)(bp + (size_t)NS * 4);
      #pragma unroll
      for (int j = 0; j < 4; ++j) {
        o[j]     += (float)a0[j];
        o[4 + j] += (float)a1[j];
      }
    }
    bf16x8 ov;
    #pragma unroll
    for (int j = 0; j < 8; ++j) ov[j] = (bf16)(o[j] * inv);
    *(bf16x8*)(at + ((s_local * 256 + c0 * 2) ^ ((s_local & 7) << 4))) = ov;
  }
  __syncthreads();

  int w = tid >> 6, l = tid & 63;
  int lr = l & 15, lg = l >> 4;
  int o_base = ot * 64 + (w >> 1) * 32;
  int sl_base = (w & 1) * 16;
  f32x4 acc[2] = {};
  #pragma unroll
  for (int k0 = 0; k0 < NC; k0 += 32) {
    bf16x8 a[2], b;
    #pragma unroll
    for (int m = 0; m < 2; ++m)
      a[m] = *(const bf16x8*)(wp + (size_t)(o_base + m * 16 + lr) * NC + k0 + lg * 8);
    {
      int row = sl_base + lr;
      b = *(const bf16x8*)(at + ((row * 256 + (k0 + lg * 8) * 2) ^ ((row & 7) << 4)));
    }
    #pragma unroll
    for (int m = 0; m < 2; ++m)
      acc[m] = mfma16(a[m], b, acc[m]);
  }
  #pragma unroll
  for (int m = 0; m < 2; ++m)
    #pragma unroll
    for (int r = 0; r < 4; ++r) {
      int o = o_base + m * 16 + lg * 4 + r;
      int sg = st * 32 + sl_base + lr;
      float v = acc[m][r] + proj_b[o] + x[(size_t)o * NS + sg];
      out[(size_t)o * NS + sg] = v * mask[sg];
    }
}

extern "C" void kernel_launch(void* const* d_in, const int* in_sizes, int n_in,
                              void* d_out, int out_size, void* d_ws, size_t ws_size,
                              hipStream_t stream) {
  const float* x      = (const float*)d_in[0];
  const float* mask   = (const float*)d_in[1];
  const float* gn_w   = (const float*)d_in[2];
  const float* gn_b   = (const float*)d_in[3];
  const float* qkv_w  = (const float*)d_in[4];
  const float* qkv_b  = (const float*)d_in[5];
  const float* proj_w = (const float*)d_in[6];
  const float* proj_b = (const float*)d_in[7];

  char* ws = (char*)d_ws;
  float* partials = (float*)(ws + 0);            //     768 B
  float* bias_s   = (float*)(ws + 1024);         //    1536 B
  bf16*  wq       = (bf16*)(ws + 4096);          //   98304 B
  bf16*  wp       = (bf16*)(ws + 102400);        //   32768 B
  bf16*  qg       = (bf16*)(ws + 135168);        // 1.50 MB [h][s][32]
  bf16*  kg       = (bf16*)(ws + 1708032);       // 1.50 MB [h][s][32]
  bf16*  vtg      = (bf16*)(ws + 3280896);       // 1.50 MB [h][c][s] (key-permuted)
  bf16*  accP     = (bf16*)(ws + 4853760);       // 6.29 MB [h][sp][cg][s][4]
  float* ml       = (float*)(ws + 11145216);     // 393 KB  [h][sp][s]
  float* out      = (float*)d_out;

  k_prep_stats<<<288, 256, 0, stream>>>(qkv_w, qkv_b, proj_w, x, wq, wp, bias_s, partials);
  k_qkv       <<<dim3(6, 96), 256, 0, stream>>>(x, partials, gn_w, gn_b, wq, bias_s, qg, kg, vtg);
  k_attn      <<<dim3(48, 4, NSPLIT), 256, 0, stream>>>(qg, kg, vtg, accP, ml);
  k_proj      <<<dim3(2, 192), 256, 0, stream>>>(wp, accP, ml, proj_b, x, mask, out);
}